// Round 1
// baseline (3390.844 us; speedup 1.0000x reference)
//
#include <hip/hip_runtime.h>
#include <hip/hip_bf16.h>

#define DEV __device__ __forceinline__

typedef __attribute__((ext_vector_type(4))) float f32x4;
typedef __attribute__((ext_vector_type(8))) short s16x8;
typedef unsigned short u16;

constexpr int Bsz = 8;      // batch
constexpr int S   = 2048;   // sequence
constexpr int Dm  = 512;    // model dim
constexpr int NHd = 8;      // heads
constexpr int FFd = 2048;
constexpr int Ln  = 4;
constexpr int T   = S * Bsz; // 16384 tokens

DEV u16 f2bf(float f) {
  union { float f; unsigned u; } v; v.f = f;
  unsigned r = v.u + 0x7fff + ((v.u >> 16) & 1);
  return (u16)(r >> 16);
}
DEV float bf2f(u16 a) { union { unsigned u; float f; } v; v.u = ((unsigned)a) << 16; return v.f; }

typedef __attribute__((address_space(1))) const unsigned int guint;
typedef __attribute__((address_space(3))) unsigned int luint;
DEV void gload16(const void* g, void* l) {
  __builtin_amdgcn_global_load_lds((guint*)g, (luint*)l, 16, 0, 0);
}

// ---------------- weight fp32 -> bf16 ----------------
__global__ void cvt_bf16_kernel(const float* __restrict__ src, u16* __restrict__ dst, int n4) {
  int i = (blockIdx.x * 256 + threadIdx.x);
  if (i >= n4) return;
  float4 v = *reinterpret_cast<const float4*>(src + i * 4);
  ushort4 o; o.x = f2bf(v.x); o.y = f2bf(v.y); o.z = f2bf(v.z); o.w = f2bf(v.w);
  *reinterpret_cast<ushort4*>(dst + i * 4) = o;
}

// ---------------- embed + positional encoding ----------------
__global__ void embed_kernel(const float* __restrict__ x, const float* __restrict__ Wemb,
                             const float* __restrict__ bemb, float* __restrict__ hf,
                             u16* __restrict__ hb) {
  int t = blockIdx.x;            // token = s*B + b
  int s = t >> 3, b = t & 7;
  const float* xr = x + ((size_t)b * S + s) * 14;
  float xv[14];
  #pragma unroll
  for (int i = 0; i < 14; i++) xv[i] = xr[i];
  for (int d = threadIdx.x; d < Dm; d += blockDim.x) {
    const float* wr = Wemb + d * 14;
    float acc = bemb[d];
    #pragma unroll
    for (int i = 0; i < 14; i++) acc += xv[i] * wr[i];
    float ang = (float)s * expf((float)((d >> 1) * 2) * (-9.210340371976184f / 512.0f));
    acc += (d & 1) ? cosf(ang) : sinf(ang);
    hf[(size_t)t * Dm + d] = acc;
    hb[(size_t)t * Dm + d] = f2bf(acc);
  }
}

// ---------------- GEMM: C(M,N) = A(M,K) @ Bt(N,K)^T + bias ----------------
// OMODE: 0 = f32 out, 1 = bf16 out, 2 = bf16 out + relu
template<int OMODE>
__global__ __launch_bounds__(256, 2)
void gemm_bt_kernel(const u16* __restrict__ A, const u16* __restrict__ Bt,
                    const float* __restrict__ bias, void* __restrict__ Cout,
                    int M, int N, int K) {
  __shared__ __align__(16) u16 As[128 * 32];
  __shared__ __align__(16) u16 Bs[128 * 32];
  const int tid = threadIdx.x;
  const int lane = tid & 63, w = tid >> 6;
  const int wr = w >> 1, wc = w & 1;
  const int lr = lane & 15, lg = lane >> 4;
  const int m0 = blockIdx.y * 128, n0 = blockIdx.x * 128;

  f32x4 acc[4][4] = {};

  const int c1 = tid, c2 = tid + 256;
  const u16* gA1 = A + (size_t)(m0 + (c1 >> 2)) * K + (c1 & 3) * 8;
  const u16* gA2 = A + (size_t)(m0 + (c2 >> 2)) * K + (c2 & 3) * 8;
  const u16* gB1 = Bt + (size_t)(n0 + (c1 >> 2)) * K + (c1 & 3) * 8;
  const u16* gB2 = Bt + (size_t)(n0 + (c2 >> 2)) * K + (c2 & 3) * 8;
  u16* lA1 = As + c1 * 8; u16* lA2 = As + c2 * 8;
  u16* lB1 = Bs + c1 * 8; u16* lB2 = Bs + c2 * 8;

  for (int kt = 0; kt < K; kt += 32) {
    __syncthreads();
    gload16(gA1 + kt, lA1); gload16(gA2 + kt, lA2);
    gload16(gB1 + kt, lB1); gload16(gB2 + kt, lB2);
    __syncthreads();
    s16x8 a[4], bb[4];
    #pragma unroll
    for (int i = 0; i < 4; i++) {
      a[i]  = *reinterpret_cast<const s16x8*>(As + ((wr * 64 + i * 16 + lr) * 32 + lg * 8));
      bb[i] = *reinterpret_cast<const s16x8*>(Bs + ((wc * 64 + i * 16 + lr) * 32 + lg * 8));
    }
    #pragma unroll
    for (int mi = 0; mi < 4; mi++)
      #pragma unroll
      for (int ni = 0; ni < 4; ni++)
        acc[mi][ni] = __builtin_amdgcn_mfma_f32_16x16x32_bf16(a[mi], bb[ni], acc[mi][ni], 0, 0, 0);
  }

  #pragma unroll
  for (int mi = 0; mi < 4; mi++) {
    int row = m0 + wr * 64 + mi * 16 + lg * 4;
    #pragma unroll
    for (int ni = 0; ni < 4; ni++) {
      int col = n0 + wc * 64 + ni * 16 + lr;
      float bv = bias[col];
      #pragma unroll
      for (int r = 0; r < 4; r++) {
        float v = acc[mi][ni][r] + bv;
        if (OMODE == 2) v = v > 0.f ? v : 0.f;
        if (OMODE == 0) ((float*)Cout)[(size_t)(row + r) * N + col] = v;
        else            ((u16*)Cout)[(size_t)(row + r) * N + col] = f2bf(v);
      }
    }
  }
}

// ---------------- V transpose: vt[(b*NH+h)*64+d][s] = qkv[t(s,b)][1024+h*64+d] ----------------
__global__ void vtrans_kernel(const u16* __restrict__ qkv, u16* __restrict__ vt) {
  __shared__ u16 tile[64][66];
  int st = blockIdx.x, b = blockIdx.y, h = blockIdx.z;
  int tid = threadIdx.x;
  #pragma unroll
  for (int p = 0; p < 4; p++) {
    int s = p * 16 + (tid >> 4);
    int dq = (tid & 15) * 4;
    size_t tok = (size_t)(st * 64 + s) * Bsz + b;
    ushort4 val = *reinterpret_cast<const ushort4*>(qkv + tok * 1536 + 1024 + h * 64 + dq);
    tile[s][dq] = val.x; tile[s][dq + 1] = val.y; tile[s][dq + 2] = val.z; tile[s][dq + 3] = val.w;
  }
  __syncthreads();
  #pragma unroll
  for (int p = 0; p < 4; p++) {
    int d = p * 16 + (tid >> 4);
    int s4 = (tid & 15) * 4;
    ushort4 o;
    o.x = tile[s4][d]; o.y = tile[s4 + 1][d]; o.z = tile[s4 + 2][d]; o.w = tile[s4 + 3][d];
    *reinterpret_cast<ushort4*>(vt + ((size_t)(b * NHd + h) * 64 + d) * S + st * 64 + s4) = o;
  }
}

// ---------------- flash attention (bidirectional, windowed via s_base) ----------------
__global__ __launch_bounds__(256, 2)
void flash_kernel(const u16* __restrict__ qkv, const u16* __restrict__ vt,
                  u16* __restrict__ ctx, int S_att) {
  const int tid = threadIdx.x;
  const int lane = tid & 63, w = tid >> 6;
  const int lr = lane & 15, lg = lane >> 4;
  const int combo = blockIdx.y, h = blockIdx.z;
  const int b = combo & 7, n = combo >> 3;
  const int s_base = n * S_att;
  const int q0 = blockIdx.x * 64 + w * 16;

  __shared__ __align__(16) u16 p_lds_all[4][16][72];
  u16 (*p_lds)[72] = p_lds_all[w];

  s16x8 qf[2];
  {
    size_t tq = (size_t)(s_base + q0 + lr) * Bsz + b;
    const u16* qp = qkv + tq * 1536 + h * 64 + lg * 8;
    qf[0] = *reinterpret_cast<const s16x8*>(qp);
    qf[1] = *reinterpret_cast<const s16x8*>(qp + 32);
  }

  float mrow[4], lrow[4]; f32x4 oacc[4];
  #pragma unroll
  for (int r = 0; r < 4; r++) { mrow[r] = -1e30f; lrow[r] = 0.f; }
  #pragma unroll
  for (int nt = 0; nt < 4; nt++) oacc[nt] = (f32x4){0.f, 0.f, 0.f, 0.f};

  const size_t vt_row = (size_t)(b * NHd + h) * 64;

  for (int kb = 0; kb < S_att; kb += 64) {
    f32x4 sg[4];
    #pragma unroll
    for (int g = 0; g < 4; g++) {
      size_t tk = (size_t)(s_base + kb + g * 16 + lr) * Bsz + b;
      const u16* kp = qkv + tk * 1536 + 512 + h * 64 + lg * 8;
      s16x8 k0 = *reinterpret_cast<const s16x8*>(kp);
      s16x8 k1 = *reinterpret_cast<const s16x8*>(kp + 32);
      f32x4 sc = (f32x4){0.f, 0.f, 0.f, 0.f};
      sc = __builtin_amdgcn_mfma_f32_16x16x32_bf16(qf[0], k0, sc, 0, 0, 0);
      sc = __builtin_amdgcn_mfma_f32_16x16x32_bf16(qf[1], k1, sc, 0, 0, 0);
      sg[g] = sc * 0.125f;
    }

    float pex[4][4];
    #pragma unroll
    for (int r = 0; r < 4; r++) {
      float mx = fmaxf(fmaxf(sg[0][r], sg[1][r]), fmaxf(sg[2][r], sg[3][r]));
      #pragma unroll
      for (int o = 8; o >= 1; o >>= 1) mx = fmaxf(mx, __shfl_xor(mx, o, 64));
      float mnew = fmaxf(mrow[r], mx);
      float corr = __expf(mrow[r] - mnew);
      float rs = 0.f;
      #pragma unroll
      for (int g = 0; g < 4; g++) { float p = __expf(sg[g][r] - mnew); pex[g][r] = p; rs += p; }
      #pragma unroll
      for (int o = 8; o >= 1; o >>= 1) rs += __shfl_xor(rs, o, 64);
      lrow[r] = lrow[r] * corr + rs;
      mrow[r] = mnew;
      #pragma unroll
      for (int nt = 0; nt < 4; nt++) oacc[nt][r] *= corr;
    }

    // P -> LDS (layout fix-up for the PV MFMA A-operand)
    asm volatile("s_waitcnt lgkmcnt(0)" ::: "memory");  // WAR vs previous iter's reads
    #pragma unroll
    for (int g = 0; g < 4; g++)
      #pragma unroll
      for (int r = 0; r < 4; r++)
        p_lds[lg * 4 + r][g * 16 + lr] = f2bf(pex[g][r]);
    asm volatile("s_waitcnt lgkmcnt(0)" ::: "memory");  // RAW: writes visible to all lanes

    #pragma unroll
    for (int kc = 0; kc < 2; kc++) {
      s16x8 pa = *reinterpret_cast<const s16x8*>(&p_lds[lr][kc * 32 + lg * 8]);
      const u16* vb = vt + vt_row * S + s_base + kb + kc * 32 + lg * 8;
      #pragma unroll
      for (int nt = 0; nt < 4; nt++) {
        s16x8 vf = *reinterpret_cast<const s16x8*>(vb + (size_t)(nt * 16 + lr) * S);
        oacc[nt] = __builtin_amdgcn_mfma_f32_16x16x32_bf16(pa, vf, oacc[nt], 0, 0, 0);
      }
    }
  }

  #pragma unroll
  for (int nt = 0; nt < 4; nt++)
    #pragma unroll
    for (int r = 0; r < 4; r++) {
      float v = oacc[nt][r] / lrow[r];
      size_t tq = (size_t)(s_base + q0 + lg * 4 + r) * Bsz + b;
      ctx[tq * 512 + h * 64 + nt * 16 + lr] = f2bf(v);
    }
}

// ---------------- residual add + LayerNorm ----------------
template<int NADD>
__global__ void ln_kernel(const float* __restrict__ hin, const float* __restrict__ a1,
                          const float* __restrict__ a2, const float* __restrict__ gamma,
                          const float* __restrict__ beta, float* __restrict__ hf,
                          u16* __restrict__ hb) {
  int row = blockIdx.x * 4 + (threadIdx.x >> 6);
  int lane = threadIdx.x & 63;
  size_t base = (size_t)row * 512 + lane * 8;
  float v[8];
  float sum = 0.f;
  #pragma unroll
  for (int j = 0; j < 8; j++) {
    float t = hin[base + j] + a1[base + j];
    if (NADD == 2) t += a2[base + j];
    v[j] = t; sum += t;
  }
  #pragma unroll
  for (int o = 32; o >= 1; o >>= 1) sum += __shfl_xor(sum, o, 64);
  float mean = sum * (1.0f / 512.0f);
  float sq = 0.f;
  #pragma unroll
  for (int j = 0; j < 8; j++) { float d = v[j] - mean; sq += d * d; }
  #pragma unroll
  for (int o = 32; o >= 1; o >>= 1) sq += __shfl_xor(sq, o, 64);
  float rstd = rsqrtf(sq * (1.0f / 512.0f) + 1e-5f);
  #pragma unroll
  for (int j = 0; j < 8; j++) {
    int d = lane * 8 + j;
    float o = (v[j] - mean) * rstd * gamma[d] + beta[d];
    hf[base + j] = o;
    hb[base + j] = f2bf(o);
  }
}

// ---------------- final projection ----------------
__global__ void out_kernel(const float* __restrict__ hf, const float* __restrict__ Wout,
                           const float* __restrict__ bout, float* __restrict__ out) {
  int b = blockIdx.x; int lane = threadIdx.x;
  size_t base = ((size_t)(S - 1) * Bsz + b) * 512;
  float s = 0.f;
  #pragma unroll
  for (int j = 0; j < 8; j++) { int d = lane * 8 + j; s += hf[base + d] * Wout[d]; }
  #pragma unroll
  for (int o = 32; o >= 1; o >>= 1) s += __shfl_xor(s, o, 64);
  if (lane == 0) out[b] = s + bout[0];
}

extern "C" void kernel_launch(void* const* d_in, const int* in_sizes, int n_in,
                              void* d_out, int out_size, void* d_ws, size_t ws_size,
                              hipStream_t stream) {
  (void)in_sizes; (void)n_in; (void)out_size; (void)ws_size;
  const float* x      = (const float*)d_in[0];
  const float* W_emb  = (const float*)d_in[1];
  const float* b_emb  = (const float*)d_in[2];
  const float* Wqkv_g = (const float*)d_in[3];
  const float* bqkv_g = (const float*)d_in[4];
  const float* Wo_g   = (const float*)d_in[5];
  const float* bo_g   = (const float*)d_in[6];
  const float* Wqkv_l = (const float*)d_in[7];
  const float* bqkv_l = (const float*)d_in[8];
  const float* Wo_l   = (const float*)d_in[9];
  const float* bo_l   = (const float*)d_in[10];
  const float* W1     = (const float*)d_in[11];
  const float* b1f    = (const float*)d_in[12];
  const float* W2     = (const float*)d_in[13];
  const float* b2f    = (const float*)d_in[14];
  const float* g1     = (const float*)d_in[15];
  const float* be1    = (const float*)d_in[16];
  const float* g2     = (const float*)d_in[17];
  const float* be2    = (const float*)d_in[18];
  const float* W_out  = (const float*)d_in[19];
  const float* b_out  = (const float*)d_in[20];
  float* out = (float*)d_out;

  char* ws = (char*)d_ws;
  u16*   w_bf = (u16*)ws;                       // 16,777,216 bf16 = 32 MiB
  float* h_f  = (float*)(ws + 33554432);        // 32 MiB
  u16*   h_b  = (u16*)(ws + 67108864);          // 16 MiB
  u16*   qkv  = (u16*)(ws + 83886080);          // 48 MiB
  u16*   vt   = (u16*)(ws + 134217728);         // 16 MiB
  u16*   ff1  = (u16*)(ws + 83886080);          // aliases qkv+vt (64 MiB)
  u16*   ctx  = (u16*)(ws + 150994944);         // 16 MiB
  float* go   = (float*)(ws + 167772160);       // 32 MiB (also ff2)
  float* lo   = (float*)(ws + 201326592);       // 32 MiB -> total 224 MiB

  u16* wqkvg = w_bf + 0;
  u16* wqkvl = w_bf + 3145728;
  u16* wog   = w_bf + 6291456;
  u16* wol   = w_bf + 7340032;
  u16* w1b   = w_bf + 8388608;
  u16* w2b   = w_bf + 12582912;

  auto cvt = [&](const float* s_, u16* d_, int n) {
    cvt_bf16_kernel<<<(n / 4 + 255) / 256, 256, 0, stream>>>(s_, d_, n / 4);
  };
  cvt(Wqkv_g, wqkvg, 3145728);
  cvt(Wqkv_l, wqkvl, 3145728);
  cvt(Wo_g,   wog,   1048576);
  cvt(Wo_l,   wol,   1048576);
  cvt(W1,     w1b,   4194304);
  cvt(W2,     w2b,   4194304);

  embed_kernel<<<T, 256, 0, stream>>>(x, W_emb, b_emb, h_f, h_b);

  for (int i = 0; i < Ln; i++) {
    // global attention
    gemm_bt_kernel<1><<<dim3(1536 / 128, T / 128), 256, 0, stream>>>(
        h_b, wqkvg + (size_t)i * 786432, bqkv_g + i * 1536, qkv, T, 1536, 512);
    vtrans_kernel<<<dim3(S / 64, Bsz, NHd), 256, 0, stream>>>(qkv, vt);
    flash_kernel<<<dim3(2048 / 64, 8, NHd), 256, 0, stream>>>(qkv, vt, ctx, 2048);
    gemm_bt_kernel<0><<<dim3(512 / 128, T / 128), 256, 0, stream>>>(
        ctx, wog + (size_t)i * 262144, bo_g + i * 512, go, T, 512, 512);
    // local (windowed) attention
    gemm_bt_kernel<1><<<dim3(1536 / 128, T / 128), 256, 0, stream>>>(
        h_b, wqkvl + (size_t)i * 786432, bqkv_l + i * 1536, qkv, T, 1536, 512);
    vtrans_kernel<<<dim3(S / 64, Bsz, NHd), 256, 0, stream>>>(qkv, vt);
    flash_kernel<<<dim3(512 / 64, 32, NHd), 256, 0, stream>>>(qkv, vt, ctx, 512);
    gemm_bt_kernel<0><<<dim3(512 / 128, T / 128), 256, 0, stream>>>(
        ctx, wol + (size_t)i * 262144, bo_l + i * 512, lo, T, 512, 512);
    // LN1
    ln_kernel<2><<<T / 4, 256, 0, stream>>>(h_f, go, lo, g1 + i * 512, be1 + i * 512, h_f, h_b);
    // FFN
    gemm_bt_kernel<2><<<dim3(FFd / 128, T / 128), 256, 0, stream>>>(
        h_b, w1b + (size_t)i * 1048576, b1f + i * 2048, ff1, T, 2048, 512);
    gemm_bt_kernel<0><<<dim3(512 / 128, T / 128), 256, 0, stream>>>(
        ff1, w2b + (size_t)i * 1048576, b2f + i * 512, go, T, 512, 2048);
    ln_kernel<1><<<T / 4, 256, 0, stream>>>(h_f, go, nullptr, g2 + i * 512, be2 + i * 512, h_f, h_b);
  }

  out_kernel<<<Bsz, 64, 0, stream>>>(h_f, W_out, b_out, out);
}